// Round 15
// baseline (76.346 us; speedup 1.0000x reference)
//
#include <hip/hip_runtime.h>
#include <hip/hip_bf16.h>

// Problem constants
#define HEIGHT 480
#define WIDTH  640
#define IN_CH  6
#define CIN    8      // p, 1-p, 6 features
#define COUT   32
#define BATCH  8
#define NPTS   16384
#define NPTOT  (BATCH * NPTS)          // 131072 = 2^17
// Padded grid: rows 0..482 (point rows 1..481), cols 0..642 (point cols 1..641)
#define GH 483
#define GW 643
#define NCELLS ((size_t)BATCH * GH * GW)   // 2,484,552 cells
#define NW64   38824                       // ceil(NCELLS/64)=38822 +guard, even

typedef float vfloat4 __attribute__((ext_vector_type(4)));  // for nontemporal stores

// grid layout: [b][gy][gx][cin], cin contiguous (32B per cell, 32B-aligned)
__device__ __forceinline__ size_t cell_idx(int b, int gy, int gx) {
    return ((size_t)b * GH + gy) * GW + gx;
}

__device__ __forceinline__ void point_cell(const float4 q, int point,
                                           int& b, int& gy, int& gx) {
    gy = (int)rintf(q.z * (float)HEIGHT) + 1;   // padded coord
    gx = (int)rintf(q.y * (float)WIDTH) + 1;
    b  = point >> 14;                           // NPTS = 16384
}

// Phase 0: zero both u64 bitmask arrays (2*NW64*8 B = 621 KB, contiguous).
__global__ void zero_masks_kernel(uint4* __restrict__ m4, int n4) {
    int i = blockIdx.x * blockDim.x + threadIdx.x;
    if (i < n4) m4[i] = make_uint4(0u, 0u, 0u, 0u);
}

// Phase 1: per point, set occupancy bit (u64 atomicOr); on collision also set
// multi bit AND zero the grid cell (idempotent - colliders write identical
// zeros; value writes happen only in the next dispatch).
__global__ void count_kernel(const float4* __restrict__ xytp,
                             unsigned long long* __restrict__ occ,
                             unsigned long long* __restrict__ multi,
                             float* __restrict__ grid) {
    int point = blockIdx.x * blockDim.x + threadIdx.x;
    if (point >= NPTOT) return;
    float4 q = xytp[point];
    int b, gy, gx;
    point_cell(q, point, b, gy, gx);
    size_t ci = cell_idx(b, gy, gx);
    size_t word = ci >> 6;
    unsigned long long bit = 1ull << (ci & 63);
    unsigned long long old = atomicOr(&occ[word], bit);
    if (old & bit) {                                  // rare (~3%)
        atomicOr(&multi[word], bit);
        float* cell = grid + (ci << 3);
        const float4 z = make_float4(0.f, 0.f, 0.f, 0.f);
        *(float4*)(cell)     = z;
        *(float4*)(cell + 4) = z;
    }
}

// Phase 2: multi bit clear (~97%) -> 32B nontemporal store (skip RFO);
// else 8 f32 HW atomics into the cell count_kernel already zeroed.
__global__ void write_kernel(const float4* __restrict__ xytp,
                             const float*  __restrict__ feats,
                             const unsigned long long* __restrict__ multi,
                             float* __restrict__ grid) {
    int point = blockIdx.x * blockDim.x + threadIdx.x;
    if (point >= NPTOT) return;
    float4 q = xytp[point];
    int b, gy, gx;
    point_cell(q, point, b, gy, gx);
    size_t ci = cell_idx(b, gy, gx);

    const float* f = feats + (size_t)point * IN_CH;
    float v0 = q.w, v1 = 1.0f - q.w;
    float f0 = f[0], f1 = f[1], f2 = f[2], f3 = f[3], f4 = f[4], f5 = f[5];

    float* cell = grid + (ci << 3);
    if (!((multi[ci >> 6] >> (ci & 63)) & 1ull)) {
        vfloat4 a = {v0, v1, f0, f1};
        vfloat4 d = {f2, f3, f4, f5};
        __builtin_nontemporal_store(a, (vfloat4*)cell);
        __builtin_nontemporal_store(d, (vfloat4*)(cell + 4));
    } else {
        unsafeAtomicAdd(cell + 0, v0);
        unsafeAtomicAdd(cell + 1, v1);
        unsafeAtomicAdd(cell + 2, f0);
        unsafeAtomicAdd(cell + 3, f1);
        unsafeAtomicAdd(cell + 4, f2);
        unsafeAtomicAdd(cell + 5, f3);
        unsafeAtomicAdd(cell + 6, f4);
        unsafeAtomicAdd(cell + 7, f5);
    }
}

// Phase 3 PROBE: conv body run 4x per thread, rep r on point (point ^ r)
// (a permutation of the point set -> representative load statistics).
// rep 0 writes the real output; reps 1-3 are kept live via asm sinks (no
// CSE/DCE possible - different points, different data). Probe dur ~= 4x conv
// -> clears the 40us fill bar and shows in top-5 WITH counters.
__global__ void __launch_bounds__(256)
conv_gather_kernel(const float4* __restrict__ xytp,
                   const float*  __restrict__ grid,
                   const unsigned long long* __restrict__ occ,
                   const float*  __restrict__ W,     // [3][3][8][32]
                   const float*  __restrict__ bias,  // [32]
                   float* __restrict__ out) {
    int point = blockIdx.x * blockDim.x + threadIdx.x;
    if (point >= NPTOT) return;

#pragma unroll 1
    for (int rep = 0; rep < 4; ++rep) {
        int pt = point ^ rep;               // rep 0: the real point
        float4 q = xytp[pt];
        int b, gy, gx;
        point_cell(q, pt, b, gy, gx);
        size_t center  = cell_idx(b, gy, gx);
        size_t base_ci = center - GW - 1;   // padded window top-left

        // Occupancy bits: one aligned u64 load per row (straddle ~3%/row).
        unsigned int occ9 = 0;
#pragma unroll
        for (int ky = 0; ky < 3; ++ky) {
            size_t ci_row = base_ci + (size_t)ky * GW;
            size_t w  = ci_row >> 6;
            int    sh = (int)(ci_row & 63);
            unsigned long long v = occ[w] >> sh;
            if (sh >= 62) v |= occ[w + 1] << (64 - sh);
            occ9 |= ((unsigned int)v & 7u) << (ky * 3);
        }

        // Loads-only masked pass (all occupied-cell loads in one window).
        float4 g0[9], g1[9];
#pragma unroll
        for (int k = 0; k < 9; ++k) {
            if (occ9 & (1u << k)) {
                size_t ci = base_ci + (size_t)(k / 3) * GW + (k % 3);
                const float* cell = grid + (ci << 3);
                g0[k] = *(const float4*)(cell);
                g1[k] = *(const float4*)(cell + 4);
            }
        }

        // Masked FMA pass.
        float acc[COUT];
#pragma unroll
        for (int c = 0; c < COUT; ++c) acc[c] = bias[c];

#pragma unroll
        for (int k = 0; k < 9; ++k) {
            if (occ9 & (1u << k)) {
                float4 a = g0[k], d = g1[k];
                float gv[CIN] = {a.x, a.y, a.z, a.w, d.x, d.y, d.z, d.w};
                const float* wp = W + k * CIN * COUT;
#pragma unroll
                for (int ci2 = 0; ci2 < CIN; ++ci2) {
#pragma unroll
                    for (int c = 0; c < COUT; ++c) {
                        acc[c] = fmaf(gv[ci2], wp[ci2 * COUT + c], acc[c]);
                    }
                }
            }
        }

        if (rep == 0) {
            float* o = out + (size_t)pt * COUT;
#pragma unroll
            for (int c = 0; c < COUT; c += 4) {
                *(float4*)(o + c) = make_float4(acc[c], acc[c + 1], acc[c + 2], acc[c + 3]);
            }
        } else {
            // Keep every acc value live (rule #17: ablation/probe must not DCE).
#pragma unroll
            for (int c = 0; c < COUT; ++c) {
                asm volatile("" :: "v"(acc[c]));
            }
        }
    }
}

extern "C" void kernel_launch(void* const* d_in, const int* in_sizes, int n_in,
                              void* d_out, int out_size, void* d_ws, size_t ws_size,
                              hipStream_t stream) {
    const float4* xytp  = (const float4*)d_in[0];   // (8,16384,4)
    const float*  feats = (const float*)d_in[1];    // (8,16384,6)
    const float*  W     = (const float*)d_in[2];    // (3,3,8,32)
    const float*  bias  = (const float*)d_in[3];    // (32,)
    float* out = (float*)d_out;                     // (8,16384,32)

    float* grid = (float*)d_ws;                     // 79.5 MB (f32 cells)
    const size_t grid_bytes = NCELLS * CIN * sizeof(float);
    unsigned long long* occ   = (unsigned long long*)((char*)d_ws + grid_bytes);
    unsigned long long* multi = occ + NW64;
    (void)ws_size;

    const int blk = 256;
    const int nblk_pts = (NPTOT + blk - 1) / blk;   // 512

    const int n4 = (2 * NW64 * 8) / 16;             // 38,824 uint4
    zero_masks_kernel<<<(n4 + blk - 1) / blk, blk, 0, stream>>>((uint4*)occ, n4);

    count_kernel<<<nblk_pts, blk, 0, stream>>>(xytp, occ, multi, grid);

    write_kernel<<<nblk_pts, blk, 0, stream>>>(xytp, feats, multi, grid);

    conv_gather_kernel<<<nblk_pts, blk, 0, stream>>>(xytp, grid, occ, W, bias, out);
}

// Round 16
// 44.228 us; speedup vs baseline: 1.7262x; 1.7262x over previous
//
#include <hip/hip_runtime.h>
#include <hip/hip_bf16.h>

// Problem constants
#define HEIGHT 480
#define WIDTH  640
#define IN_CH  6
#define CIN    8      // p, 1-p, 6 features
#define COUT   32
#define BATCH  8
#define NPTS   16384
#define NPTOT  (BATCH * NPTS)          // 131072 = 2^17
// Padded grid: rows 0..482 (point rows 1..481), cols 0..642 (point cols 1..641)
#define GH 483
#define GW 643
#define NCELLS ((size_t)BATCH * GH * GW)   // 2,484,552 cells
#define NW64   38824                       // ceil(NCELLS/64)=38822 +guard, even

// grid layout: [cell][8 x bf16] = one uint4 (16B) per cell -> ONE random
// transaction per occupied-cell gather, and the whole grid is 39.7MB
// (~L2-resident). Transaction wall ~95G/s is the binding resource.
__device__ __forceinline__ size_t cell_idx(int b, int gy, int gx) {
    return ((size_t)b * GH + gy) * GW + gx;
}

__device__ __forceinline__ void point_cell(const float4 q, int point,
                                           int& b, int& gy, int& gx) {
    gy = (int)rintf(q.z * (float)HEIGHT) + 1;   // padded coord
    gx = (int)rintf(q.y * (float)WIDTH) + 1;
    b  = point >> 14;                           // NPTS = 16384
}

__device__ __forceinline__ unsigned int pack_bf16x2(float a, float b) {
    union { __hip_bfloat162 h; unsigned int u; } cv;
    cv.h = __float22bfloat162_rn(make_float2(a, b));
    return cv.u;
}
__device__ __forceinline__ float bflo(unsigned int u) {
    return __uint_as_float(u << 16);
}
__device__ __forceinline__ float bfhi(unsigned int u) {
    return __uint_as_float(u & 0xffff0000u);
}

// Rare-path: atomic bf16-pair add via u32 CAS loop (multi cells only, ~3%).
__device__ __forceinline__ void cas_add_bf16x2(unsigned int* addr, float a, float b) {
    unsigned int oldv = *addr, assumed;
    do {
        assumed = oldv;
        unsigned int nv = pack_bf16x2(bflo(assumed) + a, bfhi(assumed) + b);
        oldv = atomicCAS(addr, assumed, nv);
    } while (oldv != assumed);
}

// Phase 0: zero both u64 bitmask arrays (2*NW64*8 B = 621 KB, contiguous).
__global__ void zero_masks_kernel(uint4* __restrict__ m4, int n4) {
    int i = blockIdx.x * blockDim.x + threadIdx.x;
    if (i < n4) m4[i] = make_uint4(0u, 0u, 0u, 0u);
}

// Phase 1: per point, set occupancy bit (u64 atomicOr); on collision also set
// multi bit AND zero the 16B grid cell (idempotent - colliders write identical
// zeros; value writes happen only in the next dispatch).
__global__ void count_kernel(const float4* __restrict__ xytp,
                             unsigned long long* __restrict__ occ,
                             unsigned long long* __restrict__ multi,
                             uint4* __restrict__ grid) {
    int point = blockIdx.x * blockDim.x + threadIdx.x;
    if (point >= NPTOT) return;
    float4 q = xytp[point];
    int b, gy, gx;
    point_cell(q, point, b, gy, gx);
    size_t ci = cell_idx(b, gy, gx);
    size_t word = ci >> 6;
    unsigned long long bit = 1ull << (ci & 63);
    unsigned long long old = atomicOr(&occ[word], bit);
    if (old & bit) {                                  // rare (~3%)
        atomicOr(&multi[word], bit);
        grid[ci] = make_uint4(0u, 0u, 0u, 0u);
    }
}

// Phase 2: multi bit clear (~97%) -> ONE plain 16B store (keep line in L2 for
// conv); else 4 u32-CAS bf16-pair adds into the cell count_kernel zeroed.
__global__ void write_kernel(const float4* __restrict__ xytp,
                             const float*  __restrict__ feats,
                             const unsigned long long* __restrict__ multi,
                             uint4* __restrict__ grid) {
    int point = blockIdx.x * blockDim.x + threadIdx.x;
    if (point >= NPTOT) return;
    float4 q = xytp[point];
    int b, gy, gx;
    point_cell(q, point, b, gy, gx);
    size_t ci = cell_idx(b, gy, gx);

    const float* f = feats + (size_t)point * IN_CH;
    float v0 = q.w, v1 = 1.0f - q.w;
    float f0 = f[0], f1 = f[1], f2 = f[2], f3 = f[3], f4 = f[4], f5 = f[5];

    if (!((multi[ci >> 6] >> (ci & 63)) & 1ull)) {
        grid[ci] = make_uint4(pack_bf16x2(v0, v1), pack_bf16x2(f0, f1),
                              pack_bf16x2(f2, f3), pack_bf16x2(f4, f5));
    } else {
        unsigned int* cw = (unsigned int*)&grid[ci];
        cas_add_bf16x2(cw + 0, v0, v1);
        cas_add_bf16x2(cw + 1, f0, f1);
        cas_add_bf16x2(cw + 2, f2, f3);
        cas_add_bf16x2(cw + 3, f4, f5);
    }
}

// Phase 3: 1 thread per point. Random transactions/point: 3 u64 occ-row
// loads (+3% straddle) + ~2.84 single-uint4 cell loads. Loads batch in one
// latency window, then masked FMA pass with bf16 unpack.
__global__ void __launch_bounds__(256)
conv_gather_kernel(const float4* __restrict__ xytp,
                   const uint4*  __restrict__ grid,
                   const unsigned long long* __restrict__ occ,
                   const float*  __restrict__ W,     // [3][3][8][32]
                   const float*  __restrict__ bias,  // [32]
                   float* __restrict__ out) {
    int point = blockIdx.x * blockDim.x + threadIdx.x;
    if (point >= NPTOT) return;
    float4 q = xytp[point];
    int b, gy, gx;
    point_cell(q, point, b, gy, gx);
    size_t center  = cell_idx(b, gy, gx);
    size_t base_ci = center - GW - 1;   // padded window top-left

    // Occupancy bits: one aligned u64 load per row (straddle load ~3%/row).
    unsigned int occ9 = 0;
#pragma unroll
    for (int ky = 0; ky < 3; ++ky) {
        size_t ci_row = base_ci + (size_t)ky * GW;
        size_t w  = ci_row >> 6;
        int    sh = (int)(ci_row & 63);
        unsigned long long v = occ[w] >> sh;
        if (sh >= 62) v |= occ[w + 1] << (64 - sh);
        occ9 |= ((unsigned int)v & 7u) << (ky * 3);
    }

    // Loads-only masked pass (all occupied-cell loads in one latency window).
    uint4 gc[9];
#pragma unroll
    for (int k = 0; k < 9; ++k) {
        if (occ9 & (1u << k)) {
            size_t ci = base_ci + (size_t)(k / 3) * GW + (k % 3);
            gc[k] = grid[ci];
        }
    }

    // Masked FMA pass (bf16 unpack is pure VALU, ~8 ops/cell).
    float acc[COUT];
#pragma unroll
    for (int c = 0; c < COUT; ++c) acc[c] = bias[c];

#pragma unroll
    for (int k = 0; k < 9; ++k) {
        if (occ9 & (1u << k)) {
            uint4 u = gc[k];
            float gv[CIN] = {bflo(u.x), bfhi(u.x), bflo(u.y), bfhi(u.y),
                             bflo(u.z), bfhi(u.z), bflo(u.w), bfhi(u.w)};
            const float* wp = W + k * CIN * COUT;
#pragma unroll
            for (int ci2 = 0; ci2 < CIN; ++ci2) {
#pragma unroll
                for (int c = 0; c < COUT; ++c) {
                    acc[c] = fmaf(gv[ci2], wp[ci2 * COUT + c], acc[c]);
                }
            }
        }
    }

    float* o = out + (size_t)point * COUT;
#pragma unroll
    for (int c = 0; c < COUT; c += 4) {
        *(float4*)(o + c) = make_float4(acc[c], acc[c + 1], acc[c + 2], acc[c + 3]);
    }
}

extern "C" void kernel_launch(void* const* d_in, const int* in_sizes, int n_in,
                              void* d_out, int out_size, void* d_ws, size_t ws_size,
                              hipStream_t stream) {
    const float4* xytp  = (const float4*)d_in[0];   // (8,16384,4)
    const float*  feats = (const float*)d_in[1];    // (8,16384,6)
    const float*  W     = (const float*)d_in[2];    // (3,3,8,32)
    const float*  bias  = (const float*)d_in[3];    // (32,)
    float* out = (float*)d_out;                     // (8,16384,32)

    uint4* grid = (uint4*)d_ws;                     // 39.7 MB (bf16 cells)
    const size_t grid_bytes = NCELLS * 16;
    unsigned long long* occ   = (unsigned long long*)((char*)d_ws + grid_bytes);
    unsigned long long* multi = occ + NW64;
    (void)ws_size;

    const int blk = 256;
    const int nblk_pts = (NPTOT + blk - 1) / blk;   // 512

    const int n4 = (2 * NW64 * 8) / 16;             // 38,824 uint4
    zero_masks_kernel<<<(n4 + blk - 1) / blk, blk, 0, stream>>>((uint4*)occ, n4);

    count_kernel<<<nblk_pts, blk, 0, stream>>>(xytp, occ, multi, grid);

    write_kernel<<<nblk_pts, blk, 0, stream>>>(xytp, feats, multi, grid);

    conv_gather_kernel<<<nblk_pts, blk, 0, stream>>>(xytp, grid, occ, W, bias, out);
}

// Round 17
// 41.793 us; speedup vs baseline: 1.8268x; 1.0583x over previous
//
#include <hip/hip_runtime.h>
#include <hip/hip_bf16.h>

// Problem constants
#define HEIGHT 480
#define WIDTH  640
#define IN_CH  6
#define CIN    8      // p, 1-p, 6 features
#define COUT   32
#define BATCH  8
#define NPTS   16384
#define NPTOT  (BATCH * NPTS)          // 131072 = 2^17
// Padded grid: rows 0..482 (point rows 1..481), cols 0..642 (point cols 1..641)
#define GH 483
#define GW 643
#define NCELLS ((size_t)BATCH * GH * GW)   // 2,484,552 cells
#define NW64   38824                       // ceil(NCELLS/64)=38822 +guard, even

typedef float vfloat4 __attribute__((ext_vector_type(4)));  // for nontemporal stores
typedef float f32x2   __attribute__((ext_vector_type(2)));  // maps to v_pk_fma_f32

// grid layout: [b][gy][gx][cin], cin contiguous (32B per cell, 32B-aligned)
__device__ __forceinline__ size_t cell_idx(int b, int gy, int gx) {
    return ((size_t)b * GH + gy) * GW + gx;
}

__device__ __forceinline__ void point_cell(const float4 q, int point,
                                           int& b, int& gy, int& gx) {
    gy = (int)rintf(q.z * (float)HEIGHT) + 1;   // padded coord
    gx = (int)rintf(q.y * (float)WIDTH) + 1;
    b  = point >> 14;                           // NPTS = 16384
}

// Phase 0: zero both u64 bitmask arrays (2*NW64*8 B = 621 KB, contiguous).
__global__ void zero_masks_kernel(uint4* __restrict__ m4, int n4) {
    int i = blockIdx.x * blockDim.x + threadIdx.x;
    if (i < n4) m4[i] = make_uint4(0u, 0u, 0u, 0u);
}

// Phase 1: per point, set occupancy bit (u64 atomicOr); on collision also set
// multi bit AND zero the grid cell (idempotent - colliders write identical
// zeros; value writes happen only in the next dispatch).
__global__ void count_kernel(const float4* __restrict__ xytp,
                             unsigned long long* __restrict__ occ,
                             unsigned long long* __restrict__ multi,
                             float* __restrict__ grid) {
    int point = blockIdx.x * blockDim.x + threadIdx.x;
    if (point >= NPTOT) return;
    float4 q = xytp[point];
    int b, gy, gx;
    point_cell(q, point, b, gy, gx);
    size_t ci = cell_idx(b, gy, gx);
    size_t word = ci >> 6;
    unsigned long long bit = 1ull << (ci & 63);
    unsigned long long old = atomicOr(&occ[word], bit);
    if (old & bit) {                                  // rare (~3%)
        atomicOr(&multi[word], bit);
        float* cell = grid + (ci << 3);
        const float4 z = make_float4(0.f, 0.f, 0.f, 0.f);
        *(float4*)(cell)     = z;
        *(float4*)(cell + 4) = z;
    }
}

// Phase 2: multi bit clear (~97%) -> 32B nontemporal store (skip RFO);
// else 8 f32 HW atomics into the cell count_kernel already zeroed.
__global__ void write_kernel(const float4* __restrict__ xytp,
                             const float*  __restrict__ feats,
                             const unsigned long long* __restrict__ multi,
                             float* __restrict__ grid) {
    int point = blockIdx.x * blockDim.x + threadIdx.x;
    if (point >= NPTOT) return;
    float4 q = xytp[point];
    int b, gy, gx;
    point_cell(q, point, b, gy, gx);
    size_t ci = cell_idx(b, gy, gx);

    const float* f = feats + (size_t)point * IN_CH;
    float v0 = q.w, v1 = 1.0f - q.w;
    float f0 = f[0], f1 = f[1], f2 = f[2], f3 = f[3], f4 = f[4], f5 = f[5];

    float* cell = grid + (ci << 3);
    if (!((multi[ci >> 6] >> (ci & 63)) & 1ull)) {
        vfloat4 a = {v0, v1, f0, f1};
        vfloat4 d = {f2, f3, f4, f5};
        __builtin_nontemporal_store(a, (vfloat4*)cell);
        __builtin_nontemporal_store(d, (vfloat4*)(cell + 4));
    } else {
        unsafeAtomicAdd(cell + 0, v0);
        unsafeAtomicAdd(cell + 1, v1);
        unsafeAtomicAdd(cell + 2, f0);
        unsafeAtomicAdd(cell + 3, f1);
        unsafeAtomicAdd(cell + 4, f2);
        unsafeAtomicAdd(cell + 5, f3);
        unsafeAtomicAdd(cell + 6, f4);
        unsafeAtomicAdd(cell + 7, f5);
    }
}

// Phase 3: 1 thread per point. Loads batch in one latency window, then a
// masked FMA pass using f32x2 vectors -> v_pk_fma_f32 (2 FMA/instr) halves
// the VALU instruction stream (wave-union makes all 9 taps execute).
__global__ void __launch_bounds__(256)
conv_gather_kernel(const float4* __restrict__ xytp,
                   const float*  __restrict__ grid,
                   const unsigned long long* __restrict__ occ,
                   const float*  __restrict__ W,     // [3][3][8][32]
                   const float*  __restrict__ bias,  // [32]
                   float* __restrict__ out) {
    int point = blockIdx.x * blockDim.x + threadIdx.x;
    if (point >= NPTOT) return;
    float4 q = xytp[point];
    int b, gy, gx;
    point_cell(q, point, b, gy, gx);
    size_t center  = cell_idx(b, gy, gx);
    size_t base_ci = center - GW - 1;   // padded window top-left

    // Occupancy bits: one aligned u64 load per row (straddle load ~3%/row).
    unsigned int occ9 = 0;
#pragma unroll
    for (int ky = 0; ky < 3; ++ky) {
        size_t ci_row = base_ci + (size_t)ky * GW;
        size_t w  = ci_row >> 6;
        int    sh = (int)(ci_row & 63);
        unsigned long long v = occ[w] >> sh;
        if (sh >= 62) v |= occ[w + 1] << (64 - sh);
        occ9 |= ((unsigned int)v & 7u) << (ky * 3);
    }

    // Loads-only masked pass (all occupied-cell loads in one latency window).
    float4 g0[9], g1[9];
#pragma unroll
    for (int k = 0; k < 9; ++k) {
        if (occ9 & (1u << k)) {
            size_t ci = base_ci + (size_t)(k / 3) * GW + (k % 3);
            const float* cell = grid + (ci << 3);
            g0[k] = *(const float4*)(cell);
            g1[k] = *(const float4*)(cell + 4);
        }
    }

    // Masked packed-FMA pass: acc as 16 x f32x2.
    const f32x2* bias2 = (const f32x2*)bias;
    f32x2 acc[16];
#pragma unroll
    for (int c = 0; c < 16; ++c) acc[c] = bias2[c];

#pragma unroll
    for (int k = 0; k < 9; ++k) {
        if (occ9 & (1u << k)) {
            float4 a = g0[k], d = g1[k];
            float gv[CIN] = {a.x, a.y, a.z, a.w, d.x, d.y, d.z, d.w};
            const float* wp = W + k * CIN * COUT;
#pragma unroll
            for (int ci2 = 0; ci2 < CIN; ++ci2) {
                const f32x2* w2 = (const f32x2*)(wp + ci2 * COUT);
                f32x2 gg = {gv[ci2], gv[ci2]};
#pragma unroll
                for (int c = 0; c < 16; ++c) {
                    acc[c] = __builtin_elementwise_fma(gg, w2[c], acc[c]);
                }
            }
        }
    }

    float* o = out + (size_t)point * COUT;
#pragma unroll
    for (int c = 0; c < 8; ++c) {
        *(float4*)(o + c * 4) = make_float4(acc[2 * c].x, acc[2 * c].y,
                                            acc[2 * c + 1].x, acc[2 * c + 1].y);
    }
}

extern "C" void kernel_launch(void* const* d_in, const int* in_sizes, int n_in,
                              void* d_out, int out_size, void* d_ws, size_t ws_size,
                              hipStream_t stream) {
    const float4* xytp  = (const float4*)d_in[0];   // (8,16384,4)
    const float*  feats = (const float*)d_in[1];    // (8,16384,6)
    const float*  W     = (const float*)d_in[2];    // (3,3,8,32)
    const float*  bias  = (const float*)d_in[3];    // (32,)
    float* out = (float*)d_out;                     // (8,16384,32)

    float* grid = (float*)d_ws;                     // 79.5 MB (f32 cells)
    const size_t grid_bytes = NCELLS * CIN * sizeof(float);
    unsigned long long* occ   = (unsigned long long*)((char*)d_ws + grid_bytes);
    unsigned long long* multi = occ + NW64;
    (void)ws_size;

    const int blk = 256;
    const int nblk_pts = (NPTOT + blk - 1) / blk;   // 512

    const int n4 = (2 * NW64 * 8) / 16;             // 38,824 uint4
    zero_masks_kernel<<<(n4 + blk - 1) / blk, blk, 0, stream>>>((uint4*)occ, n4);

    count_kernel<<<nblk_pts, blk, 0, stream>>>(xytp, occ, multi, grid);

    write_kernel<<<nblk_pts, blk, 0, stream>>>(xytp, feats, multi, grid);

    conv_gather_kernel<<<nblk_pts, blk, 0, stream>>>(xytp, grid, occ, W, bias, out);
}